// Round 3
// baseline (245.835 us; speedup 1.0000x reference)
//
#include <hip/hip_runtime.h>
#include <hip/hip_fp16.h>
#include <hip/hip_cooperative_groups.h>

// GCN, N=50000 nodes, E=800000 edges, 128->128(relu)->64, fp32 accum.
// CSR entries are 2B (src only; norm recomputed as dis[src]*dis[v]).
// r13: gemm kernel was 47us with occupancy 22% and WRITE 39MB (vs 14.6MB
//   logical): (a) 32-node tiles -> 1563 blocks (6.1/CU, LDS caps 5) for
//   real latency hiding (782 blocks = 3.05/CU was the occupancy ceiling);
//   (b) H1/H2 stores assembled in LDS (aliasing the W tile post-barrier)
//   and written as contiguous f16x8 chunks -- kills the 2B-scattered-store
//   partial-line churn that inflated HBM writes 39MB->~17MB;
//   (c) scan1+scan3+fill fused into ONE cooperative kernel (2x grid.sync),
//   saving two launches + two full-drain kernel boundaries.
// r12 carry-overs: swizzled fp16 W images built once by k_prep; linear
//   conflict-free W staging; A-frags direct global->reg; count interleaved.
// NOTE (r10): degree-sorted scheduling bought ~0; natural edge order kept.

#define Nn 50000
#define Ne 800000
#define NE2 (Ne / 2)                  // 400000 int2 edge pairs
#define SCAN_B ((Nn + 1023) / 1024)   // 49 blocks
#define GT32 ((Nn + 31) / 32)         // 1563 gemm tiles (32 nodes)

namespace cg = cooperative_groups;

using f16x8 = _Float16 __attribute__((ext_vector_type(8)));
using f32x4 = float __attribute__((ext_vector_type(4)));

// ---------------- prep: zero degi + build swizzled fp16 W images ----------------
// blocks 0..48: degi = 0 (int4 stores). block 49: W1h. block 50: W2h.
// W?h layout: chunk (c, k8) = halves W[k8*8+j][c], j=0..7, stored at
//   halves offset c*128 + ((k8 ^ (c&7)) << 3).  Readers XOR the same way;
//   stagers copy LINEARLY (the swizzle is baked into the global image).
__global__ __launch_bounds__(256) void k_prep(const float* __restrict__ W1,
                                              const float* __restrict__ W2,
                                              _Float16* __restrict__ W1h,
                                              _Float16* __restrict__ W2h,
                                              int* __restrict__ degi) {
  const int b = blockIdx.x, t = threadIdx.x;
  if (b < 49) {
    int i = b * 256 + t;
    if (i < Nn / 4) ((int4*)degi)[i] = make_int4(0, 0, 0, 0);
  } else if (b == 49) {
    // W1: fp32 [k=128][c=128] -> W1h 2048 chunks, 8 per thread
    for (int i = 0; i < 8; ++i) {
      int id = i * 256 + t;
      int c = id & 127, k8 = id >> 7;
      f16x8 hv;
      #pragma unroll
      for (int j = 0; j < 8; ++j) hv[j] = (_Float16)W1[(k8 * 8 + j) * 128 + c];
      *(f16x8*)&W1h[c * 128 + ((k8 ^ (c & 7)) << 3)] = hv;
    }
  } else {
    // W2: fp32 [k=128][c=64] -> W2h 1024 chunks, 4 per thread
    for (int i = 0; i < 4; ++i) {
      int id = i * 256 + t;
      int c = id & 63, k8 = id >> 6;
      f16x8 hv;
      #pragma unroll
      for (int j = 0; j < 8; ++j) hv[j] = (_Float16)W2[(k8 * 8 + j) * 64 + c];
      *(f16x8*)&W2h[c * 128 + ((k8 ^ (c & 7)) << 3)] = hv;
    }
  }
}

// ---------------- FUSED: layer-1 MFMA GEMM (32-node tile) + degree count ----------------
// Per block: (1) linear-stage W1h -> LDS (32KB, conflict-free);
// (2) count 256 int2 edges (1/thread; atomics overlap staging/X latency);
// (3) A-frags direct global->reg; (4) MFMA; (5) acc -> LDS (aliases Wts
//     after barrier) -> contiguous f16x8 global stores (full-line writes).
// Wave w: rows [(w&1)*16, +16), cols [(w>>1)*64, +64).
__global__ __launch_bounds__(256, 5) void k_gemm32_count(
    const float* __restrict__ X, const _Float16* __restrict__ W1h,
    __half* __restrict__ H, const int2* __restrict__ col2,
    int* __restrict__ degi, ushort2* __restrict__ rank2) {
  __shared__ _Float16 Wts[128 * 128];   // 32 KB swizzled W image; reused for out
  _Float16* Hsx = Wts;                  // [32][136] fp16 out tile (8.7 KB)

  const int tid = threadIdx.x;
  const int base = blockIdx.x * 32;

  // stage W1h -> LDS: 2048 x 16B chunks, 8 per thread, fully coalesced
  {
    const f16x8* src = (const f16x8*)W1h;
    f16x8* dst = (f16x8*)Wts;
    #pragma unroll
    for (int i = 0; i < 8; ++i) dst[i * 256 + tid] = src[i * 256 + tid];
  }

  // edge-count slice: 1 int2 per thread
  {
    int i0 = blockIdx.x * 256 + tid;
    if (i0 < NE2) {
      int2 c = col2[i0];
      ushort2 rk;
      rk.x = (unsigned short)atomicAdd(&degi[c.x], 1);
      rk.y = (unsigned short)atomicAdd(&degi[c.y], 1);
      rank2[i0] = rk;
    }
  }

  // A-fragments direct from global X
  const int w = tid >> 6, lane = tid & 63;
  const int quad = lane >> 4, mrow = lane & 15;
  const int rbase = (w & 1) * 16, cbase = (w >> 1) * 64;
  int anode = base + rbase + mrow;
  if (anode >= Nn) anode = Nn - 1;
  const float4* xg = (const float4*)(X + (size_t)anode * 128);
  f16x8 av[4];
  #pragma unroll
  for (int ko = 0; ko < 4; ++ko) {
    float4 x0 = xg[ko * 8 + quad * 2];
    float4 x1 = xg[ko * 8 + quad * 2 + 1];
    av[ko][0] = (_Float16)x0.x; av[ko][1] = (_Float16)x0.y;
    av[ko][2] = (_Float16)x0.z; av[ko][3] = (_Float16)x0.w;
    av[ko][4] = (_Float16)x1.x; av[ko][5] = (_Float16)x1.y;
    av[ko][6] = (_Float16)x1.z; av[ko][7] = (_Float16)x1.w;
  }
  __syncthreads();

  f32x4 acc[4];
  #pragma unroll
  for (int ct = 0; ct < 4; ++ct) acc[ct] = (f32x4){0.f, 0.f, 0.f, 0.f};

  #pragma unroll
  for (int ko = 0; ko < 4; ++ko) {
    #pragma unroll
    for (int ct = 0; ct < 4; ++ct) {
      int c = cbase + ct * 16 + mrow;
      f16x8 bv = *(const f16x8*)&Wts[c * 128 + (((ko * 4 + quad) ^ (c & 7)) << 3)];
      acc[ct] = __builtin_amdgcn_mfma_f32_16x16x32_f16(av[ko], bv, acc[ct], 0, 0, 0);
    }
  }

  __syncthreads();   // all waves done reading Wts; safe to alias
  #pragma unroll
  for (int ct = 0; ct < 4; ++ct) {
    #pragma unroll
    for (int r = 0; r < 4; ++r)
      Hsx[(rbase + quad * 4 + r) * 136 + cbase + ct * 16 + mrow] =
          (_Float16)acc[ct][r];
  }
  __syncthreads();

  // contiguous stores: 512 f16x8 chunks (32 rows x 16), 2 per thread
  #pragma unroll
  for (int i = 0; i < 2; ++i) {
    int id = i * 256 + tid;
    int r = id >> 4, ch = id & 15;
    int node = base + r;
    if (node < Nn)
      *(f16x8*)((_Float16*)H + (size_t)node * 128 + ch * 8) =
          *(const f16x8*)&Hsx[r * 136 + ch * 8];
  }
}

// ---------------- cooperative: scan (2 phases) + CSR fill ----------------
// 49 blocks x 1024. Phase 1: per-block exclusive scan of degi + dis.
// grid.sync. Phase 2: every block scans the 49 block sums, adds offset.
// grid.sync. Phase 3: grid-stride CSR fill (2B src, no atomics).
__global__ __launch_bounds__(1024) void k_scanfill(
    const int* __restrict__ degi, int* __restrict__ rowptr,
    float* __restrict__ dis, int* __restrict__ bsum,
    const int2* __restrict__ row2, const int2* __restrict__ col2,
    const ushort2* __restrict__ rank2, unsigned short* __restrict__ csr) {
  cg::grid_group grid = cg::this_grid();
  __shared__ int wsum[16];
  __shared__ int off_s;
  const int tid = threadIdx.x;
  const int lane = tid & 63, wid = tid >> 6;
  const int i = blockIdx.x * 1024 + tid;

  // ---- phase 1: block-local exclusive scan ----
  int v = (i < Nn) ? degi[i] : 0;
  if (i < Nn) dis[i] = rsqrtf((float)(v + 1));   // self-loop adds 1
  int incl = v;
  #pragma unroll
  for (int off = 1; off < 64; off <<= 1) {
    int t = __shfl_up(incl, off);
    if (lane >= off) incl += t;
  }
  if (lane == 63) wsum[wid] = incl;
  __syncthreads();
  if (wid == 0) {
    int wv = (lane < 16) ? wsum[lane] : 0;
    #pragma unroll
    for (int off = 1; off < 16; off <<= 1) {
      int t = __shfl_up(wv, off);
      if (lane >= off) wv += t;
    }
    if (lane < 16) wsum[lane] = wv;  // inclusive over wave totals
  }
  __syncthreads();
  int woff = (wid > 0) ? wsum[wid - 1] : 0;
  int local = woff + incl - v;                   // block-local exclusive
  if (tid == 0) bsum[blockIdx.x] = wsum[15];     // block total
  grid.sync();

  // ---- phase 2: scan the 49 block sums, add offset ----
  if (tid < 64) {
    int bv = (tid < SCAN_B) ? bsum[tid] : 0;
    int binc = bv;
    #pragma unroll
    for (int off = 1; off < 64; off <<= 1) {
      int t = __shfl_up(binc, off);
      if (tid >= off) binc += t;
    }
    if (tid == (int)blockIdx.x) off_s = binc - bv;             // exclusive
    if (blockIdx.x == 0 && tid == SCAN_B - 1) rowptr[Nn] = binc;  // == Ne
  }
  __syncthreads();
  if (i < Nn) rowptr[i] = local + off_s;
  grid.sync();

  // ---- phase 3: CSR fill, grid-stride over int2 pairs ----
  for (int t = blockIdx.x * 1024 + tid; t < NE2; t += SCAN_B * 1024) {
    int2 r = row2[t];
    int2 c = col2[t];
    ushort2 k = rank2[t];
    csr[rowptr[c.x] + (int)k.x] = (unsigned short)r.x;
    csr[rowptr[c.y] + (int)k.y] = (unsigned short)r.y;
  }
}

__device__ __forceinline__ float2 h2f(unsigned int u) {
  return __half22float2(*(const __half2*)&u);
}

// ---------------- FUSED: agg128(+b1, relu) -> LDS fp16 -> MFMA @ W2 -> H2 fp16 ----------------
// Stage A (agg): 4 nodes/wave, 16 lanes/node, uint4 (8 fp16 feats)/lane.
//   Software-pipelined csr loads (prefetch batch n+1's srcs under batch n's
//   gathers). Stage B: 16x64 MFMA against swizzled W2 image (linear stage).
//   H2 stores assembled in LDS (Hs reuse) -> contiguous f16x8 chunks.
// Nn = 50000 = 3125 * 16 exactly -> no partial blocks.
__global__ __launch_bounds__(256) void k_agg128_gemm64(
    const __half* __restrict__ H, const unsigned short* __restrict__ csr,
    const int* __restrict__ rowptr, const float* __restrict__ dis,
    const float* __restrict__ bias, const _Float16* __restrict__ W2h,
    __half* __restrict__ H2, int n) {
  __shared__ _Float16 Wts[64 * 128];   // swizzled W2 image (16KB, linear copy)
  __shared__ _Float16 Hs[16 * 136];    // 16 aggregated rows; reused for out

  const int tid = threadIdx.x;
  const int wid = tid >> 6, lane = tid & 63;
  const int sub = lane >> 4, fl = lane & 15;
  const int nb = wid * 4 + sub;                  // node-in-block [0,16)
  const int v = blockIdx.x * 16 + nb;

  // stage W2h -> LDS: 1024 x 16B chunks, linear, conflict-free
  {
    const f16x8* src = (const f16x8*)W2h;
    f16x8* dst = (f16x8*)Wts;
    #pragma unroll
    for (int i = 0; i < 4; ++i) dst[i * 256 + tid] = src[i * 256 + tid];
  }

  // ---- stage A: aggregate node v's 8 feats per lane ----
  int s = rowptr[v], e = rowptr[v + 1];
  float d = dis[v];
  float sw = d * d;                              // self-loop norm = 1/deg
  const uint4* Hq = (const uint4*)H;             // 16 uint4 per 256B row
  uint4 hv = Hq[(size_t)v * 16 + fl];
  float2 p0 = h2f(hv.x), p1 = h2f(hv.y), p2 = h2f(hv.z), p3 = h2f(hv.w);
  float a0 = p0.x * sw, a1 = p0.y * sw, a2 = p1.x * sw, a3 = p1.y * sw;
  float a4 = p2.x * sw, a5 = p2.y * sw, a6 = p3.x * sw, a7 = p3.y * sw;
  constexpr int D = 6;
  if (s < e) {
    int srcs[D];
    #pragma unroll
    for (int j = 0; j < D; ++j) {
      int idx = s + j;
      srcs[j] = csr[(idx < e) ? idx : (e - 1)];
    }
    for (int base = s; base < e; base += D) {
      uint4 q[D];
      float wd[D];
      #pragma unroll
      for (int j = 0; j < D; ++j) q[j] = Hq[(size_t)srcs[j] * 16 + fl];
      #pragma unroll
      for (int j = 0; j < D; ++j) wd[j] = dis[srcs[j]];
      int ns[D];                                 // prefetch next batch srcs
      #pragma unroll
      for (int j = 0; j < D; ++j) {
        int idx = base + D + j;
        ns[j] = csr[(idx < e) ? idx : (e - 1)];
      }
      #pragma unroll
      for (int j = 0; j < D; ++j) {
        float w = ((base + j) < e) ? wd[j] * d : 0.f;
        float2 t;
        t = h2f(q[j].x); a0 = fmaf(w, t.x, a0); a1 = fmaf(w, t.y, a1);
        t = h2f(q[j].y); a2 = fmaf(w, t.x, a2); a3 = fmaf(w, t.y, a3);
        t = h2f(q[j].z); a4 = fmaf(w, t.x, a4); a5 = fmaf(w, t.y, a5);
        t = h2f(q[j].w); a6 = fmaf(w, t.x, a6); a7 = fmaf(w, t.y, a7);
      }
      #pragma unroll
      for (int j = 0; j < D; ++j) srcs[j] = ns[j];
    }
  }
  // +b1, relu, fp16 -> LDS row nb
  {
    const float4* Bq = (const float4*)bias;
    float4 b0 = Bq[fl * 2], b1v = Bq[fl * 2 + 1];
    f16x8 hrow;
    hrow[0] = (_Float16)fmaxf(a0 + b0.x, 0.f);
    hrow[1] = (_Float16)fmaxf(a1 + b0.y, 0.f);
    hrow[2] = (_Float16)fmaxf(a2 + b0.z, 0.f);
    hrow[3] = (_Float16)fmaxf(a3 + b0.w, 0.f);
    hrow[4] = (_Float16)fmaxf(a4 + b1v.x, 0.f);
    hrow[5] = (_Float16)fmaxf(a5 + b1v.y, 0.f);
    hrow[6] = (_Float16)fmaxf(a6 + b1v.z, 0.f);
    hrow[7] = (_Float16)fmaxf(a7 + b1v.w, 0.f);
    *(f16x8*)&Hs[nb * 136 + fl * 8] = hrow;
  }
  __syncthreads();

  // ---- stage B: 16x64 = (16x128) @ (128x64), wave w -> cols [w*16, w*16+16) ----
  const int quad = lane >> 4, mrow = lane & 15;
  f32x4 acc = (f32x4){0.f, 0.f, 0.f, 0.f};
  const int c = wid * 16 + mrow;
  #pragma unroll
  for (int ko = 0; ko < 4; ++ko) {
    f16x8 avx = *(const f16x8*)&Hs[mrow * 136 + ko * 32 + quad * 8];
    f16x8 bv = *(const f16x8*)&Wts[c * 128 + (((ko * 4 + quad) ^ (c & 7)) << 3)];
    acc = __builtin_amdgcn_mfma_f32_16x16x32_f16(avx, bv, acc, 0, 0, 0);
  }

  __syncthreads();   // all waves done reading Hs; safe to alias
  #pragma unroll
  for (int r = 0; r < 4; ++r)
    Hs[(quad * 4 + r) * 136 + wid * 16 + mrow] = (_Float16)acc[r];
  __syncthreads();

  // contiguous stores: 128 f16x8 chunks (16 rows x 8), threads 0..127
  if (tid < 128) {
    int r = tid >> 3, ch = tid & 7;
    *(f16x8*)((_Float16*)H2 + ((size_t)blockIdx.x * 16 + r) * 64 + ch * 8) =
        *(const f16x8*)&Hs[r * 136 + ch * 8];
  }
}

// ---------------- aggregate 64 feats (+bias, no relu) ----------------
// 4 nodes/wave, 16 lanes/node, uint2 (4 feats) per lane; depth-8 batches,
// software-pipelined csr loads (same scheme as agg128).
__global__ __launch_bounds__(256) void k_agg64(const __half* __restrict__ H,
                                               const unsigned short* __restrict__ csr,
                                               const int* __restrict__ rowptr,
                                               const float* __restrict__ dis,
                                               const float* __restrict__ bias,
                                               float* __restrict__ Out, int n) {
  const int wid = threadIdx.x >> 6, lane = threadIdx.x & 63;
  const int sub = lane >> 4, fl = lane & 15;
  int v = blockIdx.x * 16 + wid * 4 + sub;
  if (v >= n) return;
  int s = rowptr[v], e = rowptr[v + 1];
  float d = dis[v];
  float sw = d * d;
  const uint2* Hq = (const uint2*)H;             // 16 uint2 per 128B row
  uint2 hv = Hq[(size_t)v * 16 + fl];
  float2 p0 = h2f(hv.x), p1 = h2f(hv.y);
  float a0 = p0.x * sw, a1 = p0.y * sw, a2 = p1.x * sw, a3 = p1.y * sw;
  constexpr int D = 8;
  if (s < e) {
    int srcs[D];
    #pragma unroll
    for (int j = 0; j < D; ++j) {
      int idx = s + j;
      srcs[j] = csr[(idx < e) ? idx : (e - 1)];
    }
    for (int base = s; base < e; base += D) {
      uint2 q[D];
      float wd[D];
      #pragma unroll
      for (int j = 0; j < D; ++j) q[j] = Hq[(size_t)srcs[j] * 16 + fl];
      #pragma unroll
      for (int j = 0; j < D; ++j) wd[j] = dis[srcs[j]];
      int ns[D];                                 // prefetch next batch srcs
      #pragma unroll
      for (int j = 0; j < D; ++j) {
        int idx = base + D + j;
        ns[j] = csr[(idx < e) ? idx : (e - 1)];
      }
      #pragma unroll
      for (int j = 0; j < D; ++j) {
        float w = ((base + j) < e) ? wd[j] * d : 0.f;
        float2 t;
        t = h2f(q[j].x); a0 = fmaf(w, t.x, a0); a1 = fmaf(w, t.y, a1);
        t = h2f(q[j].y); a2 = fmaf(w, t.x, a2); a3 = fmaf(w, t.y, a3);
      }
      #pragma unroll
      for (int j = 0; j < D; ++j) srcs[j] = ns[j];
    }
  }
  const float4* Bq = (const float4*)bias;
  float4 b = Bq[fl];
  float4 o = make_float4(a0 + b.x, a1 + b.y, a2 + b.z, a3 + b.w);
  ((float4*)(Out + (size_t)v * 64))[fl] = o;
}

extern "C" void kernel_launch(void* const* d_in, const int* in_sizes, int n_in,
                              void* d_out, int out_size, void* d_ws, size_t ws_size,
                              hipStream_t stream) {
  const float* x  = (const float*)d_in[0];
  const int*   ei = (const int*)d_in[1];    // [2, E] row-major
  const int*   row = ei;                    // edge_index[0] (source)
  const int*   col = ei + Ne;               // edge_index[1] (dest / segment)
  const float* W1 = (const float*)d_in[2];
  const float* b1 = (const float*)d_in[3];
  const float* W2 = (const float*)d_in[4];
  const float* b2 = (const float*)d_in[5];
  float* out = (float*)d_out;

  char* ws = (char*)d_ws;
  size_t off = 0;
  auto alloc = [&](size_t bytes) -> void* {
    void* p = ws + off;
    off += (bytes + 255) & ~(size_t)255;
    return p;
  };
  int*    degi   = (int*)   alloc(Nn * sizeof(int));       // zeroed by k_prep
  int*    rowptr = (int*)   alloc((Nn + 1) * sizeof(int));
  float*  dis    = (float*) alloc(Nn * sizeof(float));
  int*    bsum   = (int*)   alloc(64 * sizeof(int));
  unsigned short* rank = (unsigned short*)alloc((size_t)Ne * sizeof(unsigned short)); // 1.6 MB
  unsigned short* csr  = (unsigned short*)alloc((size_t)Ne * sizeof(unsigned short)); // 1.6 MB
  __half* H1     = (__half*)alloc((size_t)Nn * 128 * sizeof(__half));  // 12.8 MB
  __half* H2     = (__half*)alloc((size_t)Nn * 64 * sizeof(__half));   // 6.4 MB
  _Float16* W1h  = (_Float16*)alloc(128 * 128 * sizeof(_Float16));     // 32 KB
  _Float16* W2h  = (_Float16*)alloc(64 * 128 * sizeof(_Float16));      // 16 KB

  const int NGB = (Nn + 15) / 16;           // 3125 node groups (16 nodes each)

  // prep: degi=0 + swizzled fp16 W images (replaces hipMemsetAsync)
  k_prep<<<51, 256, 0, stream>>>(W1, W2, W1h, W2h, degi);
  // fused: layer-1 GEMM (H1 = fp16(x@W1)) + degree count (overlapped)
  k_gemm32_count<<<GT32, 256, 0, stream>>>(x, W1h, H1, (const int2*)col,
                                           degi, (ushort2*)rank);
  // cooperative: scan + rowptr + CSR fill in one launch
  {
    const int2* row2 = (const int2*)row;
    const int2* col2 = (const int2*)col;
    ushort2* rank2 = (ushort2*)rank;
    void* args[] = {(void*)&degi, (void*)&rowptr, (void*)&dis, (void*)&bsum,
                    (void*)&row2, (void*)&col2, (void*)&rank2, (void*)&csr};
    hipLaunchCooperativeKernel((void*)k_scanfill, dim3(SCAN_B), dim3(1024),
                               args, 0, stream);
  }
  // fused: H2 = fp16( relu(agg(H1) + b1) @ W2 )
  k_agg128_gemm64<<<NGB, 256, 0, stream>>>(H1, csr, rowptr, dis, b1, W2h, H2, Nn);
  // layer 2 agg: out = agg(H2) + b2
  k_agg64<<<NGB, 256, 0, stream>>>(H2, csr, rowptr, dis, b2, out, Nn);
}

// Round 4
// 185.875 us; speedup vs baseline: 1.3226x; 1.3226x over previous
//
#include <hip/hip_runtime.h>
#include <hip/hip_fp16.h>

// GCN, N=50000 nodes, E=800000 edges, 128->128(relu)->64, fp32 accum.
// CSR entries are 2B (src only).
// r14: (a) REVERT r13's cooperative scanfill (58us @ 6% occupancy: the
//   49-block grid, sized for the scan, ran the 800K-scatter fill on 1/6
//   of the machine). scan1/scan3 back to separate tiny kernels.
//   (b) SEPARABLE NORM: out[v] = dis[v]*(Hp[v] + sum_src Hp[src]) with
//   Hp[s] = dis[s]*H[s]. Pipeline reordered count->scan->gemm so the
//   layer-1 GEMM folds dis into the fp32 acc BEFORE the one fp16 rounding
//   (no extra rounding error); agg kernels lose the per-edge dis[src]
//   dependent load + per-edge multiply, and D goes 6->8 gathers in flight.
//   agg128 writes H2p = dis*H2 the same way (fp32 pre-round).
//   (c) CSR fill now hides under the GEMM (fill only needs rowptr); W
//   image prep rides the count launch. Same launch count as r12.
// r13 carry: 32-node gemm tiles (1563 blocks = 6.1/CU), LDS-assembled
//   full-line H1/H2 stores. r12 carry: swizzled fp16 W images, linear
//   conflict-free W staging, A-frags global->reg.
// NOTE (r10): degree-sorted scheduling bought ~0; natural edge order kept.

#define Nn 50000
#define Ne 800000
#define NE2 (Ne / 2)                  // 400000 int2 edge pairs
#define SCAN_B ((Nn + 1023) / 1024)   // 49 blocks
#define GT32 ((Nn + 31) / 32)         // 1563 gemm tiles (32 nodes)
#define E1B ((NE2 + 255) / 256)       // 1563 edge blocks (1 int2/thread)

using f16x8 = _Float16 __attribute__((ext_vector_type(8)));
using f32x4 = float __attribute__((ext_vector_type(4)));

// ---------------- count (+rank) + build swizzled fp16 W images ----------------
// blocks [0,E1B): degree count, 1 int2/thread. block E1B: W1h. E1B+1: W2h.
// W?h layout: chunk (c, k8) = halves W[k8*8+j][c], j=0..7, stored at
//   halves offset c*128 + ((k8 ^ (c&7)) << 3). Readers XOR the same way;
//   stagers copy LINEARLY (swizzle baked into the global image).
__global__ __launch_bounds__(256) void k_count_prep(
    const int2* __restrict__ col2, int* __restrict__ degi,
    ushort2* __restrict__ rank2, const float* __restrict__ W1,
    const float* __restrict__ W2, _Float16* __restrict__ W1h,
    _Float16* __restrict__ W2h) {
  const int b = blockIdx.x, t = threadIdx.x;
  if (b < E1B) {
    int i0 = b * 256 + t;
    if (i0 < NE2) {
      int2 c = col2[i0];
      ushort2 rk;
      rk.x = (unsigned short)atomicAdd(&degi[c.x], 1);
      rk.y = (unsigned short)atomicAdd(&degi[c.y], 1);
      rank2[i0] = rk;
    }
  } else if (b == E1B) {
    // W1: fp32 [k=128][c=128] -> W1h 2048 chunks, 8 per thread
    for (int i = 0; i < 8; ++i) {
      int id = i * 256 + t;
      int c = id & 127, k8 = id >> 7;
      f16x8 hv;
      #pragma unroll
      for (int j = 0; j < 8; ++j) hv[j] = (_Float16)W1[(k8 * 8 + j) * 128 + c];
      *(f16x8*)&W1h[c * 128 + ((k8 ^ (c & 7)) << 3)] = hv;
    }
  } else {
    // W2: fp32 [k=128][c=64] -> W2h 1024 chunks, 4 per thread
    for (int i = 0; i < 4; ++i) {
      int id = i * 256 + t;
      int c = id & 63, k8 = id >> 6;
      f16x8 hv;
      #pragma unroll
      for (int j = 0; j < 8; ++j) hv[j] = (_Float16)W2[(k8 * 8 + j) * 64 + c];
      *(f16x8*)&W2h[c * 128 + ((k8 ^ (c & 7)) << 3)] = hv;
    }
  }
}

// ---------------- scan phase 1: block-local exclusive scan + dis ----------------
__global__ __launch_bounds__(1024) void k_scan1(const int* __restrict__ degi,
                                                int* __restrict__ rowptr,
                                                float* __restrict__ dis,
                                                int* __restrict__ bsum) {
  __shared__ int wsum[16];
  int tid = threadIdx.x;
  int lane = tid & 63, wid = tid >> 6;
  int i = blockIdx.x * 1024 + tid;
  int v = (i < Nn) ? degi[i] : 0;
  if (i < Nn) dis[i] = rsqrtf((float)(v + 1));   // self-loop adds 1
  int incl = v;
  #pragma unroll
  for (int off = 1; off < 64; off <<= 1) {
    int t = __shfl_up(incl, off);
    if (lane >= off) incl += t;
  }
  if (lane == 63) wsum[wid] = incl;
  __syncthreads();
  if (wid == 0) {
    int wv = (lane < 16) ? wsum[lane] : 0;
    #pragma unroll
    for (int off = 1; off < 16; off <<= 1) {
      int t = __shfl_up(wv, off);
      if (lane >= off) wv += t;
    }
    if (lane < 16) wsum[lane] = wv;  // inclusive over wave totals
  }
  __syncthreads();
  int woff = (wid > 0) ? wsum[wid - 1] : 0;
  if (i < Nn) rowptr[i] = woff + incl - v;       // block-local exclusive
  if (tid == 0) bsum[blockIdx.x] = wsum[15];     // block total
}

// ---------------- scan phase 2+3 fused: each block scans the 49 block sums ----------------
__global__ __launch_bounds__(1024) void k_scan3(int* __restrict__ rowptr,
                                                const int* __restrict__ bsum) {
  __shared__ int off_s;
  int tid = threadIdx.x;
  if (tid < 64) {
    int v = (tid < SCAN_B) ? bsum[tid] : 0;
    int incl = v;
    #pragma unroll
    for (int off = 1; off < 64; off <<= 1) {
      int t = __shfl_up(incl, off);
      if (tid >= off) incl += t;
    }
    if (tid == (int)blockIdx.x) off_s = incl - v;          // exclusive offset
    if (blockIdx.x == 0 && tid == SCAN_B - 1) rowptr[Nn] = incl;  // == Ne
  }
  __syncthreads();
  int i = blockIdx.x * 1024 + tid;
  if (i < Nn) rowptr[i] += off_s;
}

// ---------------- FUSED: layer-1 MFMA GEMM (32-node tile, dis-scaled) + CSR fill ----------------
// Per block: (1) linear-stage W1h -> LDS (32KB, conflict-free);
// (2) fill 256 int2 edges (scatter hides under staging/X latency);
// (3) A-frags direct global->reg; (4) MFMA; (5) acc*dis[node] -> LDS
//     (aliases Wts post-barrier) -> contiguous f16x8 stores (full lines).
// Wave w: rows [(w&1)*16, +16), cols [(w>>1)*64, +64).
__global__ __launch_bounds__(256, 5) void k_gemm32_fill(
    const float* __restrict__ X, const _Float16* __restrict__ W1h,
    const float* __restrict__ dis, __half* __restrict__ H,
    const int2* __restrict__ row2, const int2* __restrict__ col2,
    const int* __restrict__ rowptr, const ushort2* __restrict__ rank2,
    unsigned short* __restrict__ csr) {
  __shared__ _Float16 Wts[128 * 128];   // 32 KB swizzled W image; reused for out
  _Float16* Hsx = Wts;                  // [32][136] fp16 out tile (8.7 KB)

  const int tid = threadIdx.x;
  const int base = blockIdx.x * 32;

  // stage W1h -> LDS: 2048 x 16B chunks, 8 per thread, fully coalesced
  {
    const f16x8* src = (const f16x8*)W1h;
    f16x8* dst = (f16x8*)Wts;
    #pragma unroll
    for (int i = 0; i < 8; ++i) dst[i * 256 + tid] = src[i * 256 + tid];
  }

  // CSR fill slice: 1 int2 per thread (needs rowptr+rank only)
  {
    int t = blockIdx.x * 256 + tid;
    if (t < NE2) {
      int2 r = row2[t];
      int2 c = col2[t];
      ushort2 k = rank2[t];
      csr[rowptr[c.x] + (int)k.x] = (unsigned short)r.x;
      csr[rowptr[c.y] + (int)k.y] = (unsigned short)r.y;
    }
  }

  // A-fragments direct from global X
  const int w = tid >> 6, lane = tid & 63;
  const int quad = lane >> 4, mrow = lane & 15;
  const int rbase = (w & 1) * 16, cbase = (w >> 1) * 64;
  int anode = base + rbase + mrow;
  if (anode >= Nn) anode = Nn - 1;
  const float4* xg = (const float4*)(X + (size_t)anode * 128);
  f16x8 av[4];
  #pragma unroll
  for (int ko = 0; ko < 4; ++ko) {
    float4 x0 = xg[ko * 8 + quad * 2];
    float4 x1 = xg[ko * 8 + quad * 2 + 1];
    av[ko][0] = (_Float16)x0.x; av[ko][1] = (_Float16)x0.y;
    av[ko][2] = (_Float16)x0.z; av[ko][3] = (_Float16)x0.w;
    av[ko][4] = (_Float16)x1.x; av[ko][5] = (_Float16)x1.y;
    av[ko][6] = (_Float16)x1.z; av[ko][7] = (_Float16)x1.w;
  }

  // dis for this lane's 4 output rows (folded into acc pre-rounding)
  float dv[4];
  #pragma unroll
  for (int r = 0; r < 4; ++r) {
    int node = base + rbase + quad * 4 + r;
    dv[r] = dis[(node < Nn) ? node : (Nn - 1)];
  }
  __syncthreads();

  f32x4 acc[4];
  #pragma unroll
  for (int ct = 0; ct < 4; ++ct) acc[ct] = (f32x4){0.f, 0.f, 0.f, 0.f};

  #pragma unroll
  for (int ko = 0; ko < 4; ++ko) {
    #pragma unroll
    for (int ct = 0; ct < 4; ++ct) {
      int c = cbase + ct * 16 + mrow;
      f16x8 bv = *(const f16x8*)&Wts[c * 128 + (((ko * 4 + quad) ^ (c & 7)) << 3)];
      acc[ct] = __builtin_amdgcn_mfma_f32_16x16x32_f16(av[ko], bv, acc[ct], 0, 0, 0);
    }
  }

  __syncthreads();   // all waves done reading Wts; safe to alias
  #pragma unroll
  for (int ct = 0; ct < 4; ++ct) {
    #pragma unroll
    for (int r = 0; r < 4; ++r)
      Hsx[(rbase + quad * 4 + r) * 136 + cbase + ct * 16 + mrow] =
          (_Float16)(acc[ct][r] * dv[r]);   // H1p = dis * (x@W1), one rounding
  }
  __syncthreads();

  // contiguous stores: 512 f16x8 chunks (32 rows x 16), 2 per thread
  #pragma unroll
  for (int i = 0; i < 2; ++i) {
    int id = i * 256 + tid;
    int r = id >> 4, ch = id & 15;
    int node = base + r;
    if (node < Nn)
      *(f16x8*)((_Float16*)H + (size_t)node * 128 + ch * 8) =
          *(const f16x8*)&Hsx[r * 136 + ch * 8];
  }
}

__device__ __forceinline__ float2 h2f(unsigned int u) {
  return __half22float2(*(const __half2*)&u);
}

// ---------------- FUSED: agg128(+b1, relu) -> LDS fp16 -> MFMA @ W2 -> H2p fp16 ----------------
// Stage A: plain sums of pre-scaled H1p rows (NO per-edge dis load/mult);
//   row = relu(dis[v]*sum + b1). 4 nodes/wave, 16 lanes/node, uint4/lane,
//   D=8 gathers in flight + batch-ahead csr prefetch.
// Stage B: 16x64 MFMA vs swizzled W2 image; stores H2p = dis[node]*H2
//   (fp32 pre-round) via LDS as contiguous f16x8 chunks.
// Nn = 50000 = 3125 * 16 exactly -> no partial blocks.
__global__ __launch_bounds__(256) void k_agg128_gemm64(
    const __half* __restrict__ H, const unsigned short* __restrict__ csr,
    const int* __restrict__ rowptr, const float* __restrict__ dis,
    const float* __restrict__ bias, const _Float16* __restrict__ W2h,
    __half* __restrict__ H2, int n) {
  __shared__ _Float16 Wts[64 * 128];   // swizzled W2 image (16KB, linear copy)
  __shared__ _Float16 Hs[16 * 136];    // 16 aggregated rows; reused for out

  const int tid = threadIdx.x;
  const int wid = tid >> 6, lane = tid & 63;
  const int sub = lane >> 4, fl = lane & 15;
  const int nb = wid * 4 + sub;                  // node-in-block [0,16)
  const int v = blockIdx.x * 16 + nb;

  // stage W2h -> LDS: 1024 x 16B chunks, linear, conflict-free
  {
    const f16x8* src = (const f16x8*)W2h;
    f16x8* dst = (f16x8*)Wts;
    #pragma unroll
    for (int i = 0; i < 4; ++i) dst[i * 256 + tid] = src[i * 256 + tid];
  }

  // ---- stage A: sum H1p over neighbors (self row included, unscaled) ----
  int s = rowptr[v], e = rowptr[v + 1];
  float d = dis[v];
  const uint4* Hq = (const uint4*)H;             // 16 uint4 per 256B row
  uint4 hv = Hq[(size_t)v * 16 + fl];
  float2 p0 = h2f(hv.x), p1 = h2f(hv.y), p2 = h2f(hv.z), p3 = h2f(hv.w);
  float a0 = p0.x, a1 = p0.y, a2 = p1.x, a3 = p1.y;
  float a4 = p2.x, a5 = p2.y, a6 = p3.x, a7 = p3.y;
  constexpr int D = 8;
  if (s < e) {
    int srcs[D];
    #pragma unroll
    for (int j = 0; j < D; ++j) {
      int idx = s + j;
      srcs[j] = csr[(idx < e) ? idx : (e - 1)];
    }
    int base = s;
    for (; base + D <= e; base += D) {           // full batches: plain adds
      uint4 q[D];
      #pragma unroll
      for (int j = 0; j < D; ++j) q[j] = Hq[(size_t)srcs[j] * 16 + fl];
      int ns[D];                                 // prefetch next batch srcs
      #pragma unroll
      for (int j = 0; j < D; ++j) {
        int idx = base + D + j;
        ns[j] = csr[(idx < e) ? idx : (e - 1)];
      }
      #pragma unroll
      for (int j = 0; j < D; ++j) {
        float2 t;
        t = h2f(q[j].x); a0 += t.x; a1 += t.y;
        t = h2f(q[j].y); a2 += t.x; a3 += t.y;
        t = h2f(q[j].z); a4 += t.x; a5 += t.y;
        t = h2f(q[j].w); a6 += t.x; a7 += t.y;
      }
      #pragma unroll
      for (int j = 0; j < D; ++j) srcs[j] = ns[j];
    }
    if (base < e) {                              // masked tail batch
      uint4 q[D];
      #pragma unroll
      for (int j = 0; j < D; ++j) q[j] = Hq[(size_t)srcs[j] * 16 + fl];
      #pragma unroll
      for (int j = 0; j < D; ++j) {
        float m = (base + j < e) ? 1.f : 0.f;
        float2 t;
        t = h2f(q[j].x); a0 = fmaf(m, t.x, a0); a1 = fmaf(m, t.y, a1);
        t = h2f(q[j].y); a2 = fmaf(m, t.x, a2); a3 = fmaf(m, t.y, a3);
        t = h2f(q[j].z); a4 = fmaf(m, t.x, a4); a5 = fmaf(m, t.y, a5);
        t = h2f(q[j].w); a6 = fmaf(m, t.x, a6); a7 = fmaf(m, t.y, a7);
      }
    }
  }
  // row = relu(dis[v]*sum + b1), fp16 -> LDS row nb
  {
    const float4* Bq = (const float4*)bias;
    float4 b0 = Bq[fl * 2], b1v = Bq[fl * 2 + 1];
    f16x8 hrow;
    hrow[0] = (_Float16)fmaxf(fmaf(d, a0, b0.x), 0.f);
    hrow[1] = (_Float16)fmaxf(fmaf(d, a1, b0.y), 0.f);
    hrow[2] = (_Float16)fmaxf(fmaf(d, a2, b0.z), 0.f);
    hrow[3] = (_Float16)fmaxf(fmaf(d, a3, b0.w), 0.f);
    hrow[4] = (_Float16)fmaxf(fmaf(d, a4, b1v.x), 0.f);
    hrow[5] = (_Float16)fmaxf(fmaf(d, a5, b1v.y), 0.f);
    hrow[6] = (_Float16)fmaxf(fmaf(d, a6, b1v.z), 0.f);
    hrow[7] = (_Float16)fmaxf(fmaf(d, a7, b1v.w), 0.f);
    *(f16x8*)&Hs[nb * 136 + fl * 8] = hrow;
  }

  // dis for this lane's 4 H2p output rows (block rows: quad*4+r)
  const int quad = lane >> 4, mrow = lane & 15;
  float dst4[4];
  #pragma unroll
  for (int r = 0; r < 4; ++r)
    dst4[r] = dis[blockIdx.x * 16 + quad * 4 + r];
  __syncthreads();

  // ---- stage B: 16x64 = (16x128) @ (128x64), wave w -> cols [w*16, +16) ----
  f32x4 acc = (f32x4){0.f, 0.f, 0.f, 0.f};
  const int c = wid * 16 + mrow;
  #pragma unroll
  for (int ko = 0; ko < 4; ++ko) {
    f16x8 avx = *(const f16x8*)&Hs[mrow * 136 + ko * 32 + quad * 8];
    f16x8 bv = *(const f16x8*)&Wts[c * 128 + (((ko * 4 + quad) ^ (c & 7)) << 3)];
    acc = __builtin_amdgcn_mfma_f32_16x16x32_f16(avx, bv, acc, 0, 0, 0);
  }

  __syncthreads();   // all waves done reading Hs; safe to alias
  #pragma unroll
  for (int r = 0; r < 4; ++r)
    Hs[(quad * 4 + r) * 136 + wid * 16 + mrow] =
        (_Float16)(acc[r] * dst4[r]);            // H2p = dis * H2, one rounding
  __syncthreads();

  // contiguous stores: 128 f16x8 chunks (16 rows x 8), threads 0..127
  if (tid < 128) {
    int r = tid >> 3, ch = tid & 7;
    *(f16x8*)((_Float16*)H2 + ((size_t)blockIdx.x * 16 + r) * 64 + ch * 8) =
        *(const f16x8*)&Hs[r * 136 + ch * 8];
  }
}

// ---------------- aggregate 64 feats: out = dis[v]*sum(H2p) + b2 ----------------
// 4 nodes/wave, 16 lanes/node, uint2 (4 feats) per lane; D=8 batches,
// batch-ahead csr prefetch, no per-edge dis.
__global__ __launch_bounds__(256) void k_agg64(const __half* __restrict__ H,
                                               const unsigned short* __restrict__ csr,
                                               const int* __restrict__ rowptr,
                                               const float* __restrict__ dis,
                                               const float* __restrict__ bias,
                                               float* __restrict__ Out, int n) {
  const int wid = threadIdx.x >> 6, lane = threadIdx.x & 63;
  const int sub = lane >> 4, fl = lane & 15;
  int v = blockIdx.x * 16 + wid * 4 + sub;
  if (v >= n) return;
  int s = rowptr[v], e = rowptr[v + 1];
  float d = dis[v];
  const uint2* Hq = (const uint2*)H;             // 16 uint2 per 128B row
  uint2 hv = Hq[(size_t)v * 16 + fl];
  float2 p0 = h2f(hv.x), p1 = h2f(hv.y);
  float a0 = p0.x, a1 = p0.y, a2 = p1.x, a3 = p1.y;
  constexpr int D = 8;
  if (s < e) {
    int srcs[D];
    #pragma unroll
    for (int j = 0; j < D; ++j) {
      int idx = s + j;
      srcs[j] = csr[(idx < e) ? idx : (e - 1)];
    }
    int base = s;
    for (; base + D <= e; base += D) {           // full batches: plain adds
      uint2 q[D];
      #pragma unroll
      for (int j = 0; j < D; ++j) q[j] = Hq[(size_t)srcs[j] * 16 + fl];
      int ns[D];                                 // prefetch next batch srcs
      #pragma unroll
      for (int j = 0; j < D; ++j) {
        int idx = base + D + j;
        ns[j] = csr[(idx < e) ? idx : (e - 1)];
      }
      #pragma unroll
      for (int j = 0; j < D; ++j) {
        float2 t;
        t = h2f(q[j].x); a0 += t.x; a1 += t.y;
        t = h2f(q[j].y); a2 += t.x; a3 += t.y;
      }
      #pragma unroll
      for (int j = 0; j < D; ++j) srcs[j] = ns[j];
    }
    if (base < e) {                              // masked tail batch
      uint2 q[D];
      #pragma unroll
      for (int j = 0; j < D; ++j) q[j] = Hq[(size_t)srcs[j] * 16 + fl];
      #pragma unroll
      for (int j = 0; j < D; ++j) {
        float m = (base + j < e) ? 1.f : 0.f;
        float2 t;
        t = h2f(q[j].x); a0 = fmaf(m, t.x, a0); a1 = fmaf(m, t.y, a1);
        t = h2f(q[j].y); a2 = fmaf(m, t.x, a2); a3 = fmaf(m, t.y, a3);
      }
    }
  }
  const float4* Bq = (const float4*)bias;
  float4 b = Bq[fl];
  float4 o = make_float4(fmaf(d, a0, b.x), fmaf(d, a1, b.y),
                         fmaf(d, a2, b.z), fmaf(d, a3, b.w));
  ((float4*)(Out + (size_t)v * 64))[fl] = o;
}

extern "C" void kernel_launch(void* const* d_in, const int* in_sizes, int n_in,
                              void* d_out, int out_size, void* d_ws, size_t ws_size,
                              hipStream_t stream) {
  const float* x  = (const float*)d_in[0];
  const int*   ei = (const int*)d_in[1];    // [2, E] row-major
  const int*   row = ei;                    // edge_index[0] (source)
  const int*   col = ei + Ne;               // edge_index[1] (dest / segment)
  const float* W1 = (const float*)d_in[2];
  const float* b1 = (const float*)d_in[3];
  const float* W2 = (const float*)d_in[4];
  const float* b2 = (const float*)d_in[5];
  float* out = (float*)d_out;

  char* ws = (char*)d_ws;
  size_t off = 0;
  auto alloc = [&](size_t bytes) -> void* {
    void* p = ws + off;
    off += (bytes + 255) & ~(size_t)255;
    return p;
  };
  int*    degi   = (int*)   alloc(Nn * sizeof(int));
  int*    rowptr = (int*)   alloc((Nn + 1) * sizeof(int));
  float*  dis    = (float*) alloc(Nn * sizeof(float));
  int*    bsum   = (int*)   alloc(64 * sizeof(int));
  unsigned short* rank = (unsigned short*)alloc((size_t)Ne * sizeof(unsigned short)); // 1.6 MB
  unsigned short* csr  = (unsigned short*)alloc((size_t)Ne * sizeof(unsigned short)); // 1.6 MB
  __half* H1     = (__half*)alloc((size_t)Nn * 128 * sizeof(__half));  // 12.8 MB (pre-scaled)
  __half* H2     = (__half*)alloc((size_t)Nn * 64 * sizeof(__half));   // 6.4 MB (pre-scaled)
  _Float16* W1h  = (_Float16*)alloc(128 * 128 * sizeof(_Float16));     // 32 KB
  _Float16* W2h  = (_Float16*)alloc(64 * 128 * sizeof(_Float16));      // 16 KB

  const int NGB = (Nn + 15) / 16;           // 3125 node groups (16 nodes each)

  hipMemsetAsync(degi, 0, Nn * sizeof(int), stream);

  // count (+rank) + W images (count must precede scan; W blocks ride along)
  k_count_prep<<<E1B + 2, 256, 0, stream>>>((const int2*)col, degi,
                                            (ushort2*)rank, W1, W2, W1h, W2h);
  k_scan1<<<SCAN_B, 1024, 0, stream>>>(degi, rowptr, dis, bsum);
  k_scan3<<<SCAN_B, 1024, 0, stream>>>(rowptr, bsum);
  // fused: H1p = fp16(dis * (x@W1)) + CSR fill (hidden under GEMM)
  k_gemm32_fill<<<GT32, 256, 0, stream>>>(x, W1h, dis, H1, (const int2*)row,
                                          (const int2*)col, rowptr,
                                          (const ushort2*)rank, csr);
  // fused: H2p = fp16( dis * (relu(dis*sum(H1p) + b1) @ W2) )
  k_agg128_gemm64<<<NGB, 256, 0, stream>>>(H1, csr, rowptr, dis, b1, W2h, H2, Nn);
  // layer 2: out = dis * sum(H2p) + b2
  k_agg64<<<NGB, 256, 0, stream>>>(H2, csr, rowptr, dis, b2, out, Nn);
}